// Round 11
// baseline (243.205 us; speedup 1.0000x reference)
//
#include <hip/hip_runtime.h>

#define BB 8192
#define TT 2048
#define NW  64   // 32-step windows per row; one wave = one row, one lane = one window
#define CL2 32
#define WU  16   // h warmup steps (contraction ~0.4/step -> ~4e-7 residual)
#define LST 33   // LDS stride per window (words): odd -> conflict-free b32 ops

__device__ __forceinline__ float sig2(float z) {
    return __builtin_amdgcn_rcpf(1.f + __builtin_amdgcn_exp2f(z));
}
__device__ __forceinline__ float sgpr(float v) {
    return __builtin_bit_cast(float, __builtin_amdgcn_readfirstlane(__builtin_bit_cast(int, v)));
}
__device__ __forceinline__ void ld16(float* d, const float* p) {
    *(float4*)(d)      = *(const float4*)(p);
    *(float4*)(d + 4)  = *(const float4*)(p + 4);
    *(float4*)(d + 8)  = *(const float4*)(p + 8);
    *(float4*)(d + 12) = *(const float4*)(p + 12);
}

__global__ __launch_bounds__(256, 4) void bkt_fused(
    const float* __restrict__ x, const float* __restrict__ y,
    const float* __restrict__ Wxh, const float* __restrict__ Whh,
    const float* __restrict__ bh, const float* __restrict__ Wy,
    const float* __restrict__ by, const float* __restrict__ prior,
    float* __restrict__ corrects, float* __restrict__ latents,
    float* __restrict__ partials)
{
    __shared__ float lds[4 * NW * LST];                // 33.8 KB: one slice per wave
    const int tid  = blockIdx.x * 256 + threadIdx.x;   // = b*64 + c
    const int lane = threadIdx.x & 63;                 // = window c
    const int b    = tid >> 6;                         // row (uniform per wave)
    float* wls = &lds[(threadIdx.x >> 6) * NW * LST];
    const int w33 = lane * LST;
    const float NL2E = -1.44269504088896340736f;

    // ---- weights -> SGPRs, pre-scaled for exp2-based sigmoid ----
    const float wh00=sgpr(Whh[0]*NL2E),  wh01=sgpr(Whh[1]*NL2E),
                wh02=sgpr(Whh[2]*NL2E),  wh03=sgpr(Whh[3]*NL2E),
                wh10=sgpr(Whh[4]*NL2E),  wh11=sgpr(Whh[5]*NL2E),
                wh12=sgpr(Whh[6]*NL2E),  wh13=sgpr(Whh[7]*NL2E),
                wh20=sgpr(Whh[8]*NL2E),  wh21=sgpr(Whh[9]*NL2E),
                wh22=sgpr(Whh[10]*NL2E), wh23=sgpr(Whh[11]*NL2E),
                wh30=sgpr(Whh[12]*NL2E), wh31=sgpr(Whh[13]*NL2E),
                wh32=sgpr(Whh[14]*NL2E), wh33=sgpr(Whh[15]*NL2E);
    const float wx0=sgpr(Wxh[0]*NL2E), wx1=sgpr(Wxh[1]*NL2E),
                wx2=sgpr(Wxh[2]*NL2E), wx3=sgpr(Wxh[3]*NL2E);
    const float bh0=sgpr(bh[0]*NL2E), bh1=sgpr(bh[1]*NL2E),
                bh2=sgpr(bh[2]*NL2E), bh3=sgpr(bh[3]*NL2E);
    const float wy00=sgpr(Wy[0]*NL2E),  wy01=sgpr(Wy[1]*NL2E),
                wy02=sgpr(Wy[2]*NL2E),  wy03=sgpr(Wy[3]*NL2E),
                wy10=sgpr(Wy[4]*NL2E),  wy11=sgpr(Wy[5]*NL2E),
                wy12=sgpr(Wy[6]*NL2E),  wy13=sgpr(Wy[7]*NL2E),
                wy20=sgpr(Wy[8]*NL2E),  wy21=sgpr(Wy[9]*NL2E),
                wy22=sgpr(Wy[10]*NL2E), wy23=sgpr(Wy[11]*NL2E),
                wy30=sgpr(Wy[12]*NL2E), wy31=sgpr(Wy[13]*NL2E),
                wy32=sgpr(Wy[14]*NL2E), wy33=sgpr(Wy[15]*NL2E);
    const float by0=sgpr(by[0]*NL2E), by1=sgpr(by[1]*NL2E),
                by2=sgpr(by[2]*NL2E), by3=sgpr(by[3]*NL2E);

#define HSTEP(xs)                                                                   \
    {                                                                               \
        float z0 = fmaf(h3,wh30,fmaf(h2,wh20,fmaf(h1,wh10,fmaf(h0,wh00,fmaf(xs,wx0,bh0))))); \
        float z1 = fmaf(h3,wh31,fmaf(h2,wh21,fmaf(h1,wh11,fmaf(h0,wh01,fmaf(xs,wx1,bh1))))); \
        float z2 = fmaf(h3,wh32,fmaf(h2,wh22,fmaf(h1,wh12,fmaf(h0,wh02,fmaf(xs,wx2,bh2))))); \
        float z3 = fmaf(h3,wh33,fmaf(h2,wh23,fmaf(h1,wh13,fmaf(h0,wh03,fmaf(xs,wx3,bh3))))); \
        h0 = sig2(z0); h1 = sig2(z1); h2 = sig2(z2); h3 = sig2(z3);                 \
    }

    const int t0 = lane * CL2;
    const float* xr = x + (size_t)b * TT + t0;
    const float* yr = y + (size_t)b * TT + t0;
    float* crow = corrects + (size_t)b * TT;
    float* lrow = latents  + (size_t)b * TT;

    // ---- loads issued up front; warmup compute hides main-load latency ----
    float xw[16], xb[32];
    ld16(xw, x + (size_t)b * TT + (lane ? t0 - WU : 0));
    ld16(xb, xr);
    ld16(xb + 16, xr + 16);

    // ---- warmup: 16 HSTEPs (lane 0 resets to exact h=0 start) ----
    float h0 = 0.f, h1 = 0.f, h2 = 0.f, h3 = 0.f;
    HSTEP(xw[0])  HSTEP(xw[1])  HSTEP(xw[2])  HSTEP(xw[3])
    HSTEP(xw[4])  HSTEP(xw[5])  HSTEP(xw[6])  HSTEP(xw[7])
    HSTEP(xw[8])  HSTEP(xw[9])  HSTEP(xw[10]) HSTEP(xw[11])
    HSTEP(xw[12]) HSTEP(xw[13]) HSTEP(xw[14]) HSTEP(xw[15])
    if (lane == 0) { h0 = h1 = h2 = h3 = 0.f; }
    const float hv0 = h0, hv1 = h1, hv2 = h2, hv3 = h3;   // window-start snapshot

    // ---- pass 1: window (A,B) affine latent map ----
    float yb[16];
    ld16(yb, yr);                                         // prefetch y first half
    float Aacc = 1.f, Bacc = 0.f;
#define S1(s)                                                                       \
    {                                                                               \
        float zl = fmaf(h3,wy30,fmaf(h2,wy20,fmaf(h1,wy10,fmaf(h0,wy00,by0))));     \
        float zf = fmaf(h3,wy31,fmaf(h2,wy21,fmaf(h1,wy11,fmaf(h0,wy01,by1))));     \
        float pl = sig2(zl), pf = sig2(zf);                                         \
        float a = (1.f - pf) - pl;                                                  \
        Bacc = fmaf(a, Bacc, pl);                                                   \
        Aacc *= a;                                                                  \
        HSTEP(xb[s])                                                                \
    }
    S1(0)  S1(1)  S1(2)  S1(3)  S1(4)  S1(5)  S1(6)  S1(7)
    S1(8)  S1(9)  S1(10) S1(11) S1(12) S1(13) S1(14) S1(15)
    S1(16) S1(17) S1(18) S1(19) S1(20) S1(21) S1(22) S1(23)
    S1(24) S1(25) S1(26) S1(27) S1(28) S1(29) S1(30) S1(31)
#undef S1

    // ---- in-wave affine scan -> lat entering this window (verified R10) ----
    float As = Aacc, Bs = Bacc;
#pragma unroll
    for (int off = 1; off < 64; off <<= 1) {
        float Au = __shfl_up(As, off);
        float Bu = __shfl_up(Bs, off);
        if (lane >= off) { Bs = fmaf(As, Bu, Bs); As *= Au; }
    }
    const float Ae = __shfl_up(As, 1);
    const float Be = __shfl_up(Bs, 1);
    const float pr = prior[0];
    float lat = (lane == 0) ? pr : fmaf(Ae, pr, Be);

    // ---- pass 2: restore h, full outputs; c streams to LDS, l to regs ----
    h0 = hv0; h1 = hv1; h2 = hv2; h3 = hv3;
    float lacc = 0.f;
    float lb[32];

#define S2(s, o)                                                                    \
    {                                                                               \
        float zl = fmaf(h3,wy30,fmaf(h2,wy20,fmaf(h1,wy10,fmaf(h0,wy00,by0))));     \
        float zf = fmaf(h3,wy31,fmaf(h2,wy21,fmaf(h1,wy11,fmaf(h0,wy01,by1))));     \
        float zg = fmaf(h3,wy32,fmaf(h2,wy22,fmaf(h1,wy12,fmaf(h0,wy02,by2))));     \
        float zs = fmaf(h3,wy33,fmaf(h2,wy23,fmaf(h1,wy13,fmaf(h0,wy03,by3))));     \
        float pl = sig2(zl), pf = sig2(zf), pg = sig2(zg), ps = sig2(zs);           \
        float correct = fmaf(lat, (1.f - ps) - pg, pg);                             \
        float nl      = fmaf(lat, (1.f - pf) - pl, pl);                             \
        float cc  = fminf(fmaxf(correct, 1e-7f), 1.f - 1e-7f);                      \
        float arg = fmaf(yb[s], fmaf(2.f, cc, -1.f), 1.f - cc);                     \
        lacc += __builtin_amdgcn_logf(arg);                                         \
        wls[w33 + (o) + (s)] = correct;                                             \
        lb[(o)+(s)] = nl; lat = nl;                                                 \
        HSTEP(xb[(o)+(s)])                                                          \
    }
    S2(0,0)  S2(1,0)  S2(2,0)  S2(3,0)  S2(4,0)  S2(5,0)  S2(6,0)  S2(7,0)
    S2(8,0)  S2(9,0)  S2(10,0) S2(11,0) S2(12,0) S2(13,0) S2(14,0) S2(15,0)
    ld16(yb, yr + 16);                                   // second y half
    S2(0,16) S2(1,16) S2(2,16) S2(3,16) S2(4,16) S2(5,16) S2(6,16) S2(7,16)
    S2(8,16) S2(9,16) S2(10,16) S2(11,16) S2(12,16) S2(13,16) S2(14,16) S2(15,16)
#undef S2

    // ---- corrects: transposed readback; each global store instr = contiguous 1 KB ----
#pragma unroll
    for (int j = 0; j < 8; ++j) {
        const int base = (8 * j + (lane >> 3)) * LST + 4 * (lane & 7);
        float4 v = make_float4(wls[base], wls[base + 1], wls[base + 2], wls[base + 3]);
        *(float4*)(crow + j * 256 + 4 * lane) = v;
    }
    // ---- latents: dump regs to the same slice, then transposed readback ----
#pragma unroll
    for (int s = 0; s < 32; ++s) wls[w33 + s] = lb[s];
#pragma unroll
    for (int j = 0; j < 8; ++j) {
        const int base = (8 * j + (lane >> 3)) * LST + 4 * (lane & 7);
        float4 v = make_float4(wls[base], wls[base + 1], wls[base + 2], wls[base + 3]);
        *(float4*)(lrow + j * 256 + 4 * lane) = v;
    }

#pragma unroll
    for (int off = 32; off; off >>= 1) lacc += __shfl_down(lacc, off);
    if ((threadIdx.x & 63) == 0) partials[tid >> 6] = lacc;
#undef HSTEP
}

__global__ __launch_bounds__(256) void bkt_loss(const float* __restrict__ partials, int n,
                                                float* __restrict__ out_loss)
{
    __shared__ double sd[4];
    double s = 0.0;
    for (int i = threadIdx.x; i < n; i += 256) s += (double)partials[i];
#pragma unroll
    for (int off = 32; off; off >>= 1) s += __shfl_down(s, off);
    if ((threadIdx.x & 63) == 0) sd[threadIdx.x >> 6] = s;
    __syncthreads();
    if (threadIdx.x == 0) {
        double t = sd[0] + sd[1] + sd[2] + sd[3];
        *out_loss = (float)(-t * 0.69314718055994530942 / ((double)BB * (double)TT));
    }
}

extern "C" void kernel_launch(void* const* d_in, const int* in_sizes, int n_in,
                              void* d_out, int out_size, void* d_ws, size_t ws_size,
                              hipStream_t stream)
{
    const float* x     = (const float*)d_in[0];
    const float* y     = (const float*)d_in[1];
    const float* Wxh   = (const float*)d_in[2];
    const float* Whh   = (const float*)d_in[3];
    const float* bh    = (const float*)d_in[4];
    const float* Wy    = (const float*)d_in[5];
    const float* by    = (const float*)d_in[6];
    const float* prior = (const float*)d_in[7];

    float* out      = (float*)d_out;
    float* corrects = out;
    float* latents  = out + (size_t)BB * TT;
    float* lossp    = out + (size_t)2 * BB * TT;

    float* partials = (float*)d_ws;                     // 8192 floats

    const int thr = BB * NW;                            // 524288 lanes

    bkt_fused<<<thr / 256, 256, 0, stream>>>(x, y, Wxh, Whh, bh, Wy, by, prior,
                                             corrects, latents, partials);
    bkt_loss<<<1, 256, 0, stream>>>(partials, thr / 64, lossp);
}

// Round 12
// 73.851 us; speedup vs baseline: 3.2932x; 3.2932x over previous
//
#include <hip/hip_runtime.h>

#define BB 8192
#define TT 2048
#define NW  64   // 32-step windows per row; one wave = one row, one lane = one window
#define CL2 32
#define WU  16   // h warmup steps (contraction ~0.4/step -> ~4e-7 residual)
#define LST 33   // LDS stride per window (words): odd -> conflict-free b32 ops

__device__ __forceinline__ float sig2(float z) {
    return __builtin_amdgcn_rcpf(1.f + __builtin_amdgcn_exp2f(z));
}
__device__ __forceinline__ float sgpr(float v) {
    return __builtin_bit_cast(float, __builtin_amdgcn_readfirstlane(__builtin_bit_cast(int, v)));
}
__device__ __forceinline__ void ld16(float* d, const float* p) {
    *(float4*)(d)      = *(const float4*)(p);
    *(float4*)(d + 4)  = *(const float4*)(p + 4);
    *(float4*)(d + 8)  = *(const float4*)(p + 8);
    *(float4*)(d + 12) = *(const float4*)(p + 12);
}

// launch_bounds(256, 2): VGPR cap 256 -- (256,4) makes the allocator squeeze to 64
// VGPRs and spill ~290 MB to scratch (R8/R11 failure signature).
__global__ __launch_bounds__(256, 2) void bkt_fused(
    const float* __restrict__ x, const float* __restrict__ y,
    const float* __restrict__ Wxh, const float* __restrict__ Whh,
    const float* __restrict__ bh, const float* __restrict__ Wy,
    const float* __restrict__ by, const float* __restrict__ prior,
    float* __restrict__ corrects, float* __restrict__ latents,
    float* __restrict__ partials)
{
    __shared__ float lds[4 * NW * LST];                // 33.8 KB: one slice per wave
    const int tid  = blockIdx.x * 256 + threadIdx.x;   // = b*64 + c
    const int lane = threadIdx.x & 63;                 // = window c
    const int b    = tid >> 6;                         // row (uniform per wave)
    float* wls = &lds[(threadIdx.x >> 6) * NW * LST];
    const int w33 = lane * LST;
    const float NL2E = -1.44269504088896340736f;

    // ---- weights -> SGPRs, pre-scaled for exp2-based sigmoid ----
    const float wh00=sgpr(Whh[0]*NL2E),  wh01=sgpr(Whh[1]*NL2E),
                wh02=sgpr(Whh[2]*NL2E),  wh03=sgpr(Whh[3]*NL2E),
                wh10=sgpr(Whh[4]*NL2E),  wh11=sgpr(Whh[5]*NL2E),
                wh12=sgpr(Whh[6]*NL2E),  wh13=sgpr(Whh[7]*NL2E),
                wh20=sgpr(Whh[8]*NL2E),  wh21=sgpr(Whh[9]*NL2E),
                wh22=sgpr(Whh[10]*NL2E), wh23=sgpr(Whh[11]*NL2E),
                wh30=sgpr(Whh[12]*NL2E), wh31=sgpr(Whh[13]*NL2E),
                wh32=sgpr(Whh[14]*NL2E), wh33=sgpr(Whh[15]*NL2E);
    const float wx0=sgpr(Wxh[0]*NL2E), wx1=sgpr(Wxh[1]*NL2E),
                wx2=sgpr(Wxh[2]*NL2E), wx3=sgpr(Wxh[3]*NL2E);
    const float bh0=sgpr(bh[0]*NL2E), bh1=sgpr(bh[1]*NL2E),
                bh2=sgpr(bh[2]*NL2E), bh3=sgpr(bh[3]*NL2E);
    const float wy00=sgpr(Wy[0]*NL2E),  wy01=sgpr(Wy[1]*NL2E),
                wy02=sgpr(Wy[2]*NL2E),  wy03=sgpr(Wy[3]*NL2E),
                wy10=sgpr(Wy[4]*NL2E),  wy11=sgpr(Wy[5]*NL2E),
                wy12=sgpr(Wy[6]*NL2E),  wy13=sgpr(Wy[7]*NL2E),
                wy20=sgpr(Wy[8]*NL2E),  wy21=sgpr(Wy[9]*NL2E),
                wy22=sgpr(Wy[10]*NL2E), wy23=sgpr(Wy[11]*NL2E),
                wy30=sgpr(Wy[12]*NL2E), wy31=sgpr(Wy[13]*NL2E),
                wy32=sgpr(Wy[14]*NL2E), wy33=sgpr(Wy[15]*NL2E);
    const float by0=sgpr(by[0]*NL2E), by1=sgpr(by[1]*NL2E),
                by2=sgpr(by[2]*NL2E), by3=sgpr(by[3]*NL2E);

#define HSTEP(xs)                                                                   \
    {                                                                               \
        float z0 = fmaf(h3,wh30,fmaf(h2,wh20,fmaf(h1,wh10,fmaf(h0,wh00,fmaf(xs,wx0,bh0))))); \
        float z1 = fmaf(h3,wh31,fmaf(h2,wh21,fmaf(h1,wh11,fmaf(h0,wh01,fmaf(xs,wx1,bh1))))); \
        float z2 = fmaf(h3,wh32,fmaf(h2,wh22,fmaf(h1,wh12,fmaf(h0,wh02,fmaf(xs,wx2,bh2))))); \
        float z3 = fmaf(h3,wh33,fmaf(h2,wh23,fmaf(h1,wh13,fmaf(h0,wh03,fmaf(xs,wx3,bh3))))); \
        h0 = sig2(z0); h1 = sig2(z1); h2 = sig2(z2); h3 = sig2(z3);                 \
    }

    const int t0 = lane * CL2;
    const float* xr = x + (size_t)b * TT + t0;
    const float* yr = y + (size_t)b * TT + t0;
    float* crow = corrects + (size_t)b * TT;
    float* lrow = latents  + (size_t)b * TT;

    // ---- loads issued up front; warmup compute hides main-load latency ----
    float xw[16], xb[32];
    ld16(xw, x + (size_t)b * TT + (lane ? t0 - WU : 0));
    ld16(xb, xr);
    ld16(xb + 16, xr + 16);

    // ---- warmup: 16 HSTEPs (lane 0 resets to exact h=0 start) ----
    float h0 = 0.f, h1 = 0.f, h2 = 0.f, h3 = 0.f;
    HSTEP(xw[0])  HSTEP(xw[1])  HSTEP(xw[2])  HSTEP(xw[3])
    HSTEP(xw[4])  HSTEP(xw[5])  HSTEP(xw[6])  HSTEP(xw[7])
    HSTEP(xw[8])  HSTEP(xw[9])  HSTEP(xw[10]) HSTEP(xw[11])
    HSTEP(xw[12]) HSTEP(xw[13]) HSTEP(xw[14]) HSTEP(xw[15])
    if (lane == 0) { h0 = h1 = h2 = h3 = 0.f; }
    const float hv0 = h0, hv1 = h1, hv2 = h2, hv3 = h3;   // window-start snapshot

    // ---- pass 1: window (A,B) affine latent map ----
    float yb[16];
    ld16(yb, yr);                                         // prefetch y first half
    float Aacc = 1.f, Bacc = 0.f;
#define S1(s)                                                                       \
    {                                                                               \
        float zl = fmaf(h3,wy30,fmaf(h2,wy20,fmaf(h1,wy10,fmaf(h0,wy00,by0))));     \
        float zf = fmaf(h3,wy31,fmaf(h2,wy21,fmaf(h1,wy11,fmaf(h0,wy01,by1))));     \
        float pl = sig2(zl), pf = sig2(zf);                                         \
        float a = (1.f - pf) - pl;                                                  \
        Bacc = fmaf(a, Bacc, pl);                                                   \
        Aacc *= a;                                                                  \
        HSTEP(xb[s])                                                                \
    }
    S1(0)  S1(1)  S1(2)  S1(3)  S1(4)  S1(5)  S1(6)  S1(7)
    S1(8)  S1(9)  S1(10) S1(11) S1(12) S1(13) S1(14) S1(15)
    S1(16) S1(17) S1(18) S1(19) S1(20) S1(21) S1(22) S1(23)
    S1(24) S1(25) S1(26) S1(27) S1(28) S1(29) S1(30) S1(31)
#undef S1

    // ---- in-wave affine scan -> lat entering this window (verified R10) ----
    float As = Aacc, Bs = Bacc;
#pragma unroll
    for (int off = 1; off < 64; off <<= 1) {
        float Au = __shfl_up(As, off);
        float Bu = __shfl_up(Bs, off);
        if (lane >= off) { Bs = fmaf(As, Bu, Bs); As *= Au; }
    }
    const float Ae = __shfl_up(As, 1);
    const float Be = __shfl_up(Bs, 1);
    const float pr = prior[0];
    float lat = (lane == 0) ? pr : fmaf(Ae, pr, Be);

    // ---- pass 2: restore h, full outputs; c streams to LDS, l to regs ----
    h0 = hv0; h1 = hv1; h2 = hv2; h3 = hv3;
    float lacc = 0.f;
    float lb[32];
    float yc[16];
    ld16(yc, yr + 16);                                   // prefetch y second half

#define S2(yb_, s, o)                                                               \
    {                                                                               \
        float zl = fmaf(h3,wy30,fmaf(h2,wy20,fmaf(h1,wy10,fmaf(h0,wy00,by0))));     \
        float zf = fmaf(h3,wy31,fmaf(h2,wy21,fmaf(h1,wy11,fmaf(h0,wy01,by1))));     \
        float zg = fmaf(h3,wy32,fmaf(h2,wy22,fmaf(h1,wy12,fmaf(h0,wy02,by2))));     \
        float zs = fmaf(h3,wy33,fmaf(h2,wy23,fmaf(h1,wy13,fmaf(h0,wy03,by3))));     \
        float pl = sig2(zl), pf = sig2(zf), pg = sig2(zg), ps = sig2(zs);           \
        float correct = fmaf(lat, (1.f - ps) - pg, pg);                             \
        float nl      = fmaf(lat, (1.f - pf) - pl, pl);                             \
        float cc  = fminf(fmaxf(correct, 1e-7f), 1.f - 1e-7f);                      \
        float arg = fmaf(yb_[s], fmaf(2.f, cc, -1.f), 1.f - cc);                    \
        lacc += __builtin_amdgcn_logf(arg);                                         \
        wls[w33 + (o) + (s)] = correct;                                             \
        lb[(o)+(s)] = nl; lat = nl;                                                 \
        HSTEP(xb[(o)+(s)])                                                          \
    }
    S2(yb,0,0)  S2(yb,1,0)  S2(yb,2,0)  S2(yb,3,0)
    S2(yb,4,0)  S2(yb,5,0)  S2(yb,6,0)  S2(yb,7,0)
    S2(yb,8,0)  S2(yb,9,0)  S2(yb,10,0) S2(yb,11,0)
    S2(yb,12,0) S2(yb,13,0) S2(yb,14,0) S2(yb,15,0)
    S2(yc,0,16) S2(yc,1,16) S2(yc,2,16) S2(yc,3,16)
    S2(yc,4,16) S2(yc,5,16) S2(yc,6,16) S2(yc,7,16)
    S2(yc,8,16) S2(yc,9,16) S2(yc,10,16) S2(yc,11,16)
    S2(yc,12,16) S2(yc,13,16) S2(yc,14,16) S2(yc,15,16)
#undef S2

    // ---- corrects: transposed readback; each global store instr = contiguous 1 KB ----
#pragma unroll
    for (int j = 0; j < 8; ++j) {
        const int base = (8 * j + (lane >> 3)) * LST + 4 * (lane & 7);
        float4 v = make_float4(wls[base], wls[base + 1], wls[base + 2], wls[base + 3]);
        *(float4*)(crow + j * 256 + 4 * lane) = v;
    }
    // ---- latents: dump regs to the same slice, then transposed readback ----
#pragma unroll
    for (int s = 0; s < 32; ++s) wls[w33 + s] = lb[s];
#pragma unroll
    for (int j = 0; j < 8; ++j) {
        const int base = (8 * j + (lane >> 3)) * LST + 4 * (lane & 7);
        float4 v = make_float4(wls[base], wls[base + 1], wls[base + 2], wls[base + 3]);
        *(float4*)(lrow + j * 256 + 4 * lane) = v;
    }

#pragma unroll
    for (int off = 32; off; off >>= 1) lacc += __shfl_down(lacc, off);
    if ((threadIdx.x & 63) == 0) partials[tid >> 6] = lacc;
#undef HSTEP
}

__global__ __launch_bounds__(256) void bkt_loss(const float* __restrict__ partials, int n,
                                                float* __restrict__ out_loss)
{
    __shared__ double sd[4];
    double s = 0.0;
    for (int i = threadIdx.x; i < n; i += 256) s += (double)partials[i];
#pragma unroll
    for (int off = 32; off; off >>= 1) s += __shfl_down(s, off);
    if ((threadIdx.x & 63) == 0) sd[threadIdx.x >> 6] = s;
    __syncthreads();
    if (threadIdx.x == 0) {
        double t = sd[0] + sd[1] + sd[2] + sd[3];
        *out_loss = (float)(-t * 0.69314718055994530942 / ((double)BB * (double)TT));
    }
}

extern "C" void kernel_launch(void* const* d_in, const int* in_sizes, int n_in,
                              void* d_out, int out_size, void* d_ws, size_t ws_size,
                              hipStream_t stream)
{
    const float* x     = (const float*)d_in[0];
    const float* y     = (const float*)d_in[1];
    const float* Wxh   = (const float*)d_in[2];
    const float* Whh   = (const float*)d_in[3];
    const float* bh    = (const float*)d_in[4];
    const float* Wy    = (const float*)d_in[5];
    const float* by    = (const float*)d_in[6];
    const float* prior = (const float*)d_in[7];

    float* out      = (float*)d_out;
    float* corrects = out;
    float* latents  = out + (size_t)BB * TT;
    float* lossp    = out + (size_t)2 * BB * TT;

    float* partials = (float*)d_ws;                     // 8192 floats

    const int thr = BB * NW;                            // 524288 lanes

    bkt_fused<<<thr / 256, 256, 0, stream>>>(x, y, Wxh, Whh, bh, Wy, by, prior,
                                             corrects, latents, partials);
    bkt_loss<<<1, 256, 0, stream>>>(partials, thr / 64, lossp);
}